// Round 3
// baseline (925.190 us; speedup 1.0000x reference)
//
#include <hip/hip_runtime.h>
#include <cmath>

constexpr int N = 131072;     // nodes
constexpr int E = 4194304;    // edges (without self-loops)
constexpr int F = 16;         // hidden width H1

// Padded strides (floats): give each node its own cache sector so far-atomic
// per-line serialization (~400ns/op, measured r2) drops from 512 ops/line to
// ~mean-degree ops/line.
constexpr int PD = 8;         // 32B stride for deg / acc2 accumulators
constexpr int PA = 16;        // 64B stride for layer-1 feature accumulators

// ---- degree: self-loop init + per-edge atomic increment (padded) -----------
__global__ void k_deg_init(float* __restrict__ degp) {
    int i = blockIdx.x * blockDim.x + threadIdx.x;
    if (i < N) degp[(size_t)i * PD] = 1.0f;
}

__global__ void k_deg_edges(const int* __restrict__ dst, float* degp) {
    int e = blockIdx.x * blockDim.x + threadIdx.x;
    if (e < E) atomicAdd(&degp[(size_t)dst[e] * PD], 1.0f);
}

// ---- dinv, y = dinv*x (compact), seed axp with self-loop y[i] --------------
// Factorization: a[d] = dinv[d] * ( sum_{edges} y[src] + y[d] ),  y = dinv*x
__global__ void k_dinv_seed(const float* __restrict__ x,
                            const float* __restrict__ degp,
                            float* __restrict__ dinv,
                            float* __restrict__ y,
                            float* __restrict__ axp0,
                            float* __restrict__ axp1) {
    int i = blockIdx.x * blockDim.x + threadIdx.x;
    if (i >= N) return;
    float di = rsqrtf(degp[(size_t)i * PD]);
    dinv[i] = di;
    float y0 = di * x[2 * i + 0];
    float y1 = di * x[2 * i + 1];
    y[2 * i + 0] = y0;
    y[2 * i + 1] = y1;
    axp0[(size_t)i * PA] = y0;   // self-loop seed
    axp1[(size_t)i * PA] = y1;
}

// ---- layer-1 edge aggregation: 1 thread/edge, 2 atomics to 2 padded arrays -
__global__ void k_aggx(const int* __restrict__ src,
                       const int* __restrict__ dst,
                       const float* __restrict__ y,
                       float* axp0, float* axp1) {
    int e = blockIdx.x * blockDim.x + threadIdx.x;
    if (e >= E) return;
    int s = src[e];
    int d = dst[e];
    float y0 = y[2 * s + 0];
    float y1 = y[2 * s + 1];
    atomicAdd(&axp0[(size_t)d * PA], y0);
    atomicAdd(&axp1[(size_t)d * PA], y1);
}

// ---- node pass: finish layer1 (scale by dinv), relu, dot W2 -> g2; seed ----
__global__ void k_node2(const float* __restrict__ axp0,
                        const float* __restrict__ axp1,
                        const float* __restrict__ W1,
                        const float* __restrict__ b1,
                        const float* __restrict__ W2,
                        const float* __restrict__ dinv,
                        float* __restrict__ g2,
                        float* __restrict__ acc2p) {
    int i = blockIdx.x * blockDim.x + threadIdx.x;
    if (i >= N) return;
    float di = dinv[i];
    float a0 = di * axp0[(size_t)i * PA];
    float a1 = di * axp1[(size_t)i * PA];
    float acc = 0.0f;
#pragma unroll
    for (int f = 0; f < F; ++f) {
        float v = fmaf(a0, W1[f], fmaf(a1, W1[F + f], b1[f]));
        acc = fmaf(fmaxf(v, 0.0f), W2[f], acc);
    }
    float g = di * acc;          // g2 = dinv * h2
    g2[i] = g;
    acc2p[(size_t)i * PD] = g;   // self-loop seed
}

// ---- layer-2 edge aggregation: one atomic per edge (padded) ----------------
__global__ void k_agg2(const int* __restrict__ src,
                       const int* __restrict__ dst,
                       const float* __restrict__ g2,
                       float* acc2p) {
    int e = blockIdx.x * blockDim.x + threadIdx.x;
    if (e >= E) return;
    atomicAdd(&acc2p[(size_t)dst[e] * PD], g2[src[e]]);
}

// ---- sigmoid per node: scores = sigmoid(dinv*acc2 + b2) --------------------
__global__ void k_score(const float* __restrict__ acc2p,
                        const float* __restrict__ dinv,
                        const float* __restrict__ b2,
                        float* __restrict__ scores) {
    int i = blockIdx.x * blockDim.x + threadIdx.x;
    if (i >= N) return;
    float v = fmaf(dinv[i], acc2p[(size_t)i * PD], b2[0]);
    scores[i] = 1.0f / (1.0f + expf(-v));
}

// ---- gather per original edge: out[e] = scores[src[e]] ---------------------
__global__ void k_out(const int* __restrict__ src,
                      const float* __restrict__ scores,
                      float* __restrict__ out) {
    int e = blockIdx.x * blockDim.x + threadIdx.x;
    if (e >= E) return;
    out[e] = scores[src[e]];
}

extern "C" void kernel_launch(void* const* d_in, const int* in_sizes, int n_in,
                              void* d_out, int out_size, void* d_ws, size_t ws_size,
                              hipStream_t stream) {
    const float* x  = (const float*)d_in[0];   // [N,2]
    const float* W1 = (const float*)d_in[1];   // [2,16] row-major
    const float* b1 = (const float*)d_in[2];   // [16]
    const float* W2 = (const float*)d_in[3];   // [16,1]
    const float* b2 = (const float*)d_in[4];   // [1]
    const int*   ei = (const int*)d_in[5];     // [2,E]
    const int* src = ei;
    const int* dst = ei + E;

    // ws layout (floats): degp[N*PD] | acc2p[N*PD] | dinv[N] | y[2N] | g2[N] | scores[N]
    float* ws     = (float*)d_ws;
    float* degp   = ws;
    float* acc2p  = degp + (size_t)N * PD;
    float* dinv   = acc2p + (size_t)N * PD;
    float* y      = dinv + N;
    float* g2     = y + (size_t)2 * N;
    float* scores = g2 + N;

    // d_out (4M floats, dead until k_out) hosts the two padded layer-1
    // feature accumulators: axp0 | axp1, each N*PA floats = 2M.
    float* out  = (float*)d_out;
    float* axp0 = out;
    float* axp1 = out + (size_t)N * PA;

    dim3 blk(256);
    k_deg_init <<<N / 256, blk, 0, stream>>>(degp);
    k_deg_edges<<<E / 256, blk, 0, stream>>>(dst, degp);
    k_dinv_seed<<<N / 256, blk, 0, stream>>>(x, degp, dinv, y, axp0, axp1);
    k_aggx     <<<E / 256, blk, 0, stream>>>(src, dst, y, axp0, axp1);
    k_node2    <<<N / 256, blk, 0, stream>>>(axp0, axp1, W1, b1, W2, dinv, g2, acc2p);
    k_agg2     <<<E / 256, blk, 0, stream>>>(src, dst, g2, acc2p);
    k_score    <<<N / 256, blk, 0, stream>>>(acc2p, dinv, b2, scores);
    k_out      <<<E / 256, blk, 0, stream>>>(src, scores, out);
}

// Round 4
// 245.175 us; speedup vs baseline: 3.7736x; 3.7736x over previous
//
#include <hip/hip_runtime.h>
#include <cmath>

typedef unsigned int uint;

constexpr int N  = 131072;    // nodes
constexpr int E  = 4194304;   // edges (without self-loops)
constexpr int F  = 16;        // hidden width H1
constexpr int NB = 512;       // dst buckets (256 nodes each: bucket = dst>>8)
constexpr int NBLK  = 1024;   // partition blocks
constexpr int CHUNK = 4096;   // edges per partition block (NBLK*CHUNK == E)

// ---- Phase A1: per-block bucket histogram (bucket-major storage) -----------
__global__ void k_hist(const int* __restrict__ dst, uint* __restrict__ hist_blocks) {
    __shared__ uint h[NB];
    int t = threadIdx.x, g = blockIdx.x;
    h[t] = 0; h[t + 256] = 0;
    __syncthreads();
    int base = g * CHUNK;
#pragma unroll
    for (int k = 0; k < 16; ++k) {
        int d = dst[base + k * 256 + t];
        atomicAdd(&h[d >> 8], 1u);
    }
    __syncthreads();
    hist_blocks[(size_t)t * NBLK + g]         = h[t];
    hist_blocks[(size_t)(t + 256) * NBLK + g] = h[t + 256];
}

// ---- hierarchical exclusive scan of hist_blocks (512K elems) ---------------
__global__ void k_scan_up(const uint* __restrict__ hist, uint* __restrict__ bsum) {
    __shared__ uint s[256];
    int g = blockIdx.x, t = threadIdx.x;
    s[t] = hist[(size_t)g * 256 + t];
    __syncthreads();
    for (int off = 128; off > 0; off >>= 1) {
        if (t < off) s[t] += s[t + off];
        __syncthreads();
    }
    if (t == 0) bsum[g] = s[0];
}

__global__ void k_scan_mid(uint* bsum) {   // 2048 elems, one block, in-place exclusive
    __shared__ uint s[256];
    int t = threadIdx.x;
    uint v[8]; uint sum = 0;
#pragma unroll
    for (int k = 0; k < 8; ++k) { v[k] = bsum[t * 8 + k]; sum += v[k]; }
    s[t] = sum;
    __syncthreads();
    for (int off = 1; off < 256; off <<= 1) {
        uint x = (t >= off) ? s[t - off] : 0u;
        __syncthreads();
        s[t] += x;
        __syncthreads();
    }
    uint base = (t == 0) ? 0u : s[t - 1];
#pragma unroll
    for (int k = 0; k < 8; ++k) { uint old = v[k]; bsum[t * 8 + k] = base; base += old; }
}

__global__ void k_scan_down(const uint* __restrict__ hist, const uint* __restrict__ bsum,
                            uint* __restrict__ scanned) {
    __shared__ uint s[256];
    int g = blockIdx.x, t = threadIdx.x;
    uint v = hist[(size_t)g * 256 + t];
    s[t] = v;
    __syncthreads();
    for (int off = 1; off < 256; off <<= 1) {
        uint x = (t >= off) ? s[t - off] : 0u;
        __syncthreads();
        s[t] += x;
        __syncthreads();
    }
    scanned[(size_t)g * 256 + t] = bsum[g] + s[t] - v;   // exclusive
}

// ---- Phase A3: scatter edges into bucket regions, packed (src<<8|dstLow) ---
__global__ void k_scatter(const int* __restrict__ src, const int* __restrict__ dst,
                          const uint* __restrict__ scanned, uint* __restrict__ part) {
    __shared__ uint bump[NB];
    __shared__ uint basep[NB];
    int t = threadIdx.x, g = blockIdx.x;
    bump[t] = 0; bump[t + 256] = 0;
    basep[t]       = scanned[(size_t)t * NBLK + g];
    basep[t + 256] = scanned[(size_t)(t + 256) * NBLK + g];
    __syncthreads();
    int base = g * CHUNK;
#pragma unroll
    for (int k = 0; k < 16; ++k) {
        int e = base + k * 256 + t;
        int d = dst[e];
        int s = src[e];
        int b = d >> 8;
        uint pos = atomicAdd(&bump[b], 1u);
        part[basep[b] + pos] = ((uint)s << 8) | (uint)(d & 255);
    }
}

// ---- Phase B1: per-bucket degree -> dinv, y = dinv*x -----------------------
__global__ void k_bucket_deg(const uint* __restrict__ part, const uint* __restrict__ scanned,
                             const float* __restrict__ x,
                             float* __restrict__ dinv, float2* __restrict__ y) {
    __shared__ uint cnt[256];
    int t = threadIdx.x, b = blockIdx.x;
    cnt[t] = 0;
    __syncthreads();
    uint s0 = scanned[(size_t)b * NBLK];
    uint s1 = (b == NB - 1) ? (uint)E : scanned[(size_t)(b + 1) * NBLK];
    for (uint i = s0 + t; i < s1; i += 256) atomicAdd(&cnt[part[i] & 255u], 1u);
    __syncthreads();
    int node = (b << 8) + t;
    float di = rsqrtf(1.0f + (float)cnt[t]);   // +1 self-loop
    dinv[node] = di;
    float2 xv = ((const float2*)x)[node];
    y[node] = make_float2(di * xv.x, di * xv.y);
}

// ---- Phase B2: layer-1 bucket aggregation + fused MLP -> g2 = dinv*h2 ------
__global__ void k_bucket_l1(const uint* __restrict__ part, const uint* __restrict__ scanned,
                            const float2* __restrict__ y, const float* __restrict__ dinv,
                            const float* __restrict__ W1, const float* __restrict__ b1,
                            const float* __restrict__ W2, float* __restrict__ g2) {
    __shared__ float a0[256], a1[256];
    int t = threadIdx.x, b = blockIdx.x;
    a0[t] = 0.0f; a1[t] = 0.0f;
    __syncthreads();
    uint s0 = scanned[(size_t)b * NBLK];
    uint s1 = (b == NB - 1) ? (uint)E : scanned[(size_t)(b + 1) * NBLK];
    for (uint i = s0 + t; i < s1; i += 256) {
        uint pk = part[i];
        float2 ys = y[pk >> 8];
        atomicAdd(&a0[pk & 255u], ys.x);
        atomicAdd(&a1[pk & 255u], ys.y);
    }
    __syncthreads();
    int node = (b << 8) + t;
    float di = dinv[node];
    float2 yn = y[node];
    float A0 = di * (a0[t] + yn.x);            // self-loop + factored dinv[d]
    float A1 = di * (a1[t] + yn.y);
    float acc = 0.0f;
#pragma unroll
    for (int f = 0; f < F; ++f) {
        float v = fmaf(A0, W1[f], fmaf(A1, W1[F + f], b1[f]));
        acc = fmaf(fmaxf(v, 0.0f), W2[f], acc);
    }
    g2[node] = di * acc;
}

// ---- Phase B3: layer-2 bucket aggregation + sigmoid -> scores --------------
__global__ void k_bucket_l2(const uint* __restrict__ part, const uint* __restrict__ scanned,
                            const float* __restrict__ g2, const float* __restrict__ dinv,
                            const float* __restrict__ b2, float* __restrict__ scores) {
    __shared__ float a[256];
    int t = threadIdx.x, b = blockIdx.x;
    a[t] = 0.0f;
    __syncthreads();
    uint s0 = scanned[(size_t)b * NBLK];
    uint s1 = (b == NB - 1) ? (uint)E : scanned[(size_t)(b + 1) * NBLK];
    for (uint i = s0 + t; i < s1; i += 256) {
        uint pk = part[i];
        atomicAdd(&a[pk & 255u], g2[pk >> 8]);
    }
    __syncthreads();
    int node = (b << 8) + t;
    float v = fmaf(dinv[node], a[t] + g2[node], b2[0]);
    scores[node] = 1.0f / (1.0f + expf(-v));
}

// ---- output gather: out[e] = scores[src[e]] --------------------------------
__global__ void k_out(const int* __restrict__ src, const float* __restrict__ scores,
                      float* __restrict__ out) {
    int e = blockIdx.x * blockDim.x + threadIdx.x;
    if (e < E) out[e] = scores[src[e]];
}

extern "C" void kernel_launch(void* const* d_in, const int* in_sizes, int n_in,
                              void* d_out, int out_size, void* d_ws, size_t ws_size,
                              hipStream_t stream) {
    const float* x  = (const float*)d_in[0];   // [N,2]
    const float* W1 = (const float*)d_in[1];   // [2,16]
    const float* b1 = (const float*)d_in[2];   // [16]
    const float* W2 = (const float*)d_in[3];   // [16,1]
    const float* b2 = (const float*)d_in[4];   // [1]
    const int*   ei = (const int*)d_in[5];     // [2,E] (harness delivers int32)
    const int* src = ei;
    const int* dst = ei + E;

    // ws layout: hist_blocks[512K u32] | scanned[512K u32] | bsum[2048 u32]
    //          | dinv[N f32] | y[N f32x2] | g2[N f32] | scores[N f32]  (~6.6 MB)
    uint* hist_blocks = (uint*)d_ws;
    uint* scanned     = hist_blocks + (size_t)NB * NBLK;
    uint* bsum        = scanned + (size_t)NB * NBLK;
    float* dinv       = (float*)(bsum + 2048);
    float2* y         = (float2*)(dinv + N);
    float* g2         = (float*)(y + N);
    float* scores     = g2 + N;

    // packed partitioned edges (16 MB) live in d_out — dead until k_out
    uint* part  = (uint*)d_out;
    float* out  = (float*)d_out;

    dim3 blk(256);
    k_hist      <<<NBLK, blk, 0, stream>>>(dst, hist_blocks);
    k_scan_up   <<<(NB * NBLK) / 256, blk, 0, stream>>>(hist_blocks, bsum);
    k_scan_mid  <<<1, blk, 0, stream>>>(bsum);
    k_scan_down <<<(NB * NBLK) / 256, blk, 0, stream>>>(hist_blocks, bsum, scanned);
    k_scatter   <<<NBLK, blk, 0, stream>>>(src, dst, scanned, part);
    k_bucket_deg<<<NB, blk, 0, stream>>>(part, scanned, x, dinv, y);
    k_bucket_l1 <<<NB, blk, 0, stream>>>(part, scanned, y, dinv, W1, b1, W2, g2);
    k_bucket_l2 <<<NB, blk, 0, stream>>>(part, scanned, g2, dinv, b2, scores);
    k_out       <<<E / 256, blk, 0, stream>>>(src, scores, out);
}

// Round 5
// 217.359 us; speedup vs baseline: 4.2565x; 1.1280x over previous
//
#include <hip/hip_runtime.h>
#include <cmath>

typedef unsigned int uint;

constexpr int N  = 131072;    // nodes
constexpr int E  = 4194304;   // edges (without self-loops)
constexpr int F  = 16;        // hidden width H1
constexpr int NB = 512;       // dst buckets of 256 nodes (bucket = dst>>8)
constexpr int NBLK  = 512;    // partition blocks
constexpr int SCT   = 512;    // threads per partition block
constexpr int CHUNK = 8192;   // edges per partition block (NBLK*CHUNK == E)
constexpr int EPT   = 16;     // edges per thread in partition kernels
constexpr int SPLIT = 4;      // sub-blocks per bucket in aggregation passes
constexpr int NSCAN = NB * NBLK;   // 262144 hist entries

// ---- zero the degree accumulator (ws is poisoned 0xAA) ---------------------
__global__ void k_zero(float* __restrict__ degf) {
    int i = blockIdx.x * blockDim.x + threadIdx.x;
    if (i < N) degf[i] = 0.0f;
}

// ---- Phase A1: per-block bucket histogram (bucket-major storage) -----------
__global__ void k_hist(const int* __restrict__ dst, uint* __restrict__ hist_blocks) {
    __shared__ uint h[NB];
    int t = threadIdx.x, g = blockIdx.x;
    h[t] = 0;
    __syncthreads();
    int base = g * CHUNK;
#pragma unroll
    for (int k = 0; k < EPT; ++k)
        atomicAdd(&h[dst[base + k * SCT + t] >> 8], 1u);
    __syncthreads();
    hist_blocks[(size_t)t * NBLK + g] = h[t];   // [bucket][block]
}

// ---- hierarchical exclusive scan of hist_blocks (262144 elems) -------------
__global__ void k_scan_up(const uint* __restrict__ hist, uint* __restrict__ bsum) {
    __shared__ uint s[256];
    int g = blockIdx.x, t = threadIdx.x;
    s[t] = hist[(size_t)g * 256 + t];
    __syncthreads();
    for (int off = 128; off > 0; off >>= 1) {
        if (t < off) s[t] += s[t + off];
        __syncthreads();
    }
    if (t == 0) bsum[g] = s[0];
}

__global__ void k_scan_mid(uint* bsum) {   // 1024 elems, one block, exclusive in place
    __shared__ uint s[256];
    int t = threadIdx.x;
    uint v[4]; uint sum = 0;
#pragma unroll
    for (int k = 0; k < 4; ++k) { v[k] = bsum[t * 4 + k]; sum += v[k]; }
    s[t] = sum;
    __syncthreads();
    for (int off = 1; off < 256; off <<= 1) {
        uint x = (t >= off) ? s[t - off] : 0u;
        __syncthreads();
        s[t] += x;
        __syncthreads();
    }
    uint base = (t == 0) ? 0u : s[t - 1];
#pragma unroll
    for (int k = 0; k < 4; ++k) { uint old = v[k]; bsum[t * 4 + k] = base; base += old; }
}

__global__ void k_scan_down(const uint* __restrict__ hist, const uint* __restrict__ bsum,
                            uint* __restrict__ scanned) {
    __shared__ uint s[256];
    int g = blockIdx.x, t = threadIdx.x;
    uint v = hist[(size_t)g * 256 + t];
    s[t] = v;
    __syncthreads();
    for (int off = 1; off < 256; off <<= 1) {
        uint x = (t >= off) ? s[t - off] : 0u;
        __syncthreads();
        s[t] += x;
        __syncthreads();
    }
    scanned[(size_t)g * 256 + t] = bsum[g] + s[t] - v;   // exclusive
}

// ---- Phase A3: LDS-staged counting-sort scatter, ascending flush -----------
__global__ void __launch_bounds__(SCT) k_scatter(
        const int* __restrict__ src, const int* __restrict__ dst,
        const uint* __restrict__ scanned, uint* __restrict__ part) {
    __shared__ uint h[NB];       // hist -> bump
    __shared__ uint sc[NB];      // scan temp (inclusive)
    __shared__ uint wb[NB];      // write_base[b] = scanned[b][g] - excl_local[b]
    __shared__ uint vals[CHUNK];
    __shared__ uint addr[CHUNK];
    int t = threadIdx.x, g = blockIdx.x;
    h[t] = 0;
    __syncthreads();
    int d[EPT], s[EPT];
    int base = g * CHUNK;
#pragma unroll
    for (int k = 0; k < EPT; ++k) {
        int e = base + k * SCT + t;
        d[k] = dst[e];
        s[k] = src[e];
        atomicAdd(&h[d[k] >> 8], 1u);
    }
    __syncthreads();
    uint v = h[t];
    sc[t] = v;
    __syncthreads();
    for (int off = 1; off < NB; off <<= 1) {      // Hillis-Steele inclusive, 512 wide
        uint x = (t >= off) ? sc[t - off] : 0u;
        __syncthreads();
        sc[t] += x;
        __syncthreads();
    }
    uint ex = sc[t] - v;                          // local exclusive prefix
    wb[t] = scanned[(size_t)t * NBLK + g] - ex;
    h[t] = ex;                                    // bump counter starts at excl
    __syncthreads();
#pragma unroll
    for (int k = 0; k < EPT; ++k) {
        int b = d[k] >> 8;
        uint slot = atomicAdd(&h[b], 1u);
        vals[slot] = ((uint)s[k] << 8) | (uint)(d[k] & 255);
        addr[slot] = wb[b] + slot;                // strictly ascending in slot
    }
    __syncthreads();
#pragma unroll
    for (int k = 0; k < EPT; ++k) {
        int i = k * SCT + t;
        part[addr[i]] = vals[i];
    }
}

// ---- Phase B1: degree counts (SPLIT blocks/bucket, contiguous atomic flush)
__global__ void k_deg(const uint* __restrict__ part, const uint* __restrict__ scanned,
                      float* __restrict__ degf) {
    __shared__ uint cnt[256];
    int t = threadIdx.x;
    int b = blockIdx.x >> 2, sub = blockIdx.x & (SPLIT - 1);
    cnt[t] = 0;
    __syncthreads();
    uint S0 = scanned[(size_t)b * NBLK];
    uint S1 = (b == NB - 1) ? (uint)E : scanned[(size_t)(b + 1) * NBLK];
    uint len = S1 - S0, per = (len + SPLIT - 1) / SPLIT;
    uint i0 = S0 + sub * per;
    uint i1 = i0 + per; if (i1 > S1) i1 = S1;
    for (uint i = i0 + t; i < i1; i += 256) atomicAdd(&cnt[part[i] & 255u], 1u);
    __syncthreads();
    if (cnt[t]) atomicAdd(&degf[(b << 8) + t], (float)cnt[t]);
}

// ---- dinv, y = dinv*x, seed ax with self-loop y ----------------------------
__global__ void k_dinv(const float* __restrict__ x, const float* __restrict__ degf,
                       float* __restrict__ dinv, float2* __restrict__ y,
                       float* __restrict__ ax0, float* __restrict__ ax1) {
    int i = blockIdx.x * blockDim.x + threadIdx.x;
    if (i >= N) return;
    float di = rsqrtf(1.0f + degf[i]);           // +1 self-loop
    dinv[i] = di;
    float2 xv = ((const float2*)x)[i];
    float y0 = di * xv.x, y1 = di * xv.y;
    y[i] = make_float2(y0, y1);
    ax0[i] = y0;                                  // self-loop seed
    ax1[i] = y1;
}

// ---- Phase B2: layer-1 aggregation (SPLIT blocks/bucket) -------------------
__global__ void k_l1(const uint* __restrict__ part, const uint* __restrict__ scanned,
                     const float2* __restrict__ y,
                     float* __restrict__ ax0, float* __restrict__ ax1) {
    __shared__ float a0[256], a1[256];
    int t = threadIdx.x;
    int b = blockIdx.x >> 2, sub = blockIdx.x & (SPLIT - 1);
    a0[t] = 0.0f; a1[t] = 0.0f;
    __syncthreads();
    uint S0 = scanned[(size_t)b * NBLK];
    uint S1 = (b == NB - 1) ? (uint)E : scanned[(size_t)(b + 1) * NBLK];
    uint len = S1 - S0, per = (len + SPLIT - 1) / SPLIT;
    uint i0 = S0 + sub * per;
    uint i1 = i0 + per; if (i1 > S1) i1 = S1;
    for (uint i = i0 + t; i < i1; i += 256) {
        uint pk = part[i];
        float2 ys = y[pk >> 8];
        atomicAdd(&a0[pk & 255u], ys.x);
        atomicAdd(&a1[pk & 255u], ys.y);
    }
    __syncthreads();
    int node = (b << 8) + t;
    atomicAdd(&ax0[node], a0[t]);                 // contiguous -> coalesced
    atomicAdd(&ax1[node], a1[t]);
}

// ---- node MLP: finish layer1, relu, dot W2 -> g2; seed acc2 ----------------
__global__ void k_node2(const float* __restrict__ ax0, const float* __restrict__ ax1,
                        const float* __restrict__ W1, const float* __restrict__ b1,
                        const float* __restrict__ W2, const float* __restrict__ dinv,
                        float* __restrict__ g2, float* __restrict__ acc2) {
    int i = blockIdx.x * blockDim.x + threadIdx.x;
    if (i >= N) return;
    float di = dinv[i];
    float A0 = di * ax0[i];
    float A1 = di * ax1[i];
    float acc = 0.0f;
#pragma unroll
    for (int f = 0; f < F; ++f) {
        float v = fmaf(A0, W1[f], fmaf(A1, W1[F + f], b1[f]));
        acc = fmaf(fmaxf(v, 0.0f), W2[f], acc);
    }
    float g = di * acc;
    g2[i] = g;
    acc2[i] = g;                                  // self-loop seed
}

// ---- Phase B3: layer-2 aggregation (SPLIT blocks/bucket) -------------------
__global__ void k_l2(const uint* __restrict__ part, const uint* __restrict__ scanned,
                     const float* __restrict__ g2, float* __restrict__ acc2) {
    __shared__ float a[256];
    int t = threadIdx.x;
    int b = blockIdx.x >> 2, sub = blockIdx.x & (SPLIT - 1);
    a[t] = 0.0f;
    __syncthreads();
    uint S0 = scanned[(size_t)b * NBLK];
    uint S1 = (b == NB - 1) ? (uint)E : scanned[(size_t)(b + 1) * NBLK];
    uint len = S1 - S0, per = (len + SPLIT - 1) / SPLIT;
    uint i0 = S0 + sub * per;
    uint i1 = i0 + per; if (i1 > S1) i1 = S1;
    for (uint i = i0 + t; i < i1; i += 256) {
        uint pk = part[i];
        atomicAdd(&a[pk & 255u], g2[pk >> 8]);
    }
    __syncthreads();
    atomicAdd(&acc2[(b << 8) + t], a[t]);
}

// ---- sigmoid per node ------------------------------------------------------
__global__ void k_score(const float* __restrict__ acc2, const float* __restrict__ dinv,
                        const float* __restrict__ b2, float* __restrict__ scores) {
    int i = blockIdx.x * blockDim.x + threadIdx.x;
    if (i >= N) return;
    float v = fmaf(dinv[i], acc2[i], b2[0]);
    scores[i] = 1.0f / (1.0f + expf(-v));
}

// ---- output gather: out[e] = scores[src[e]] --------------------------------
__global__ void k_out(const int* __restrict__ src, const float* __restrict__ scores,
                      float* __restrict__ out) {
    int e = blockIdx.x * blockDim.x + threadIdx.x;
    if (e < E) out[e] = scores[src[e]];
}

extern "C" void kernel_launch(void* const* d_in, const int* in_sizes, int n_in,
                              void* d_out, int out_size, void* d_ws, size_t ws_size,
                              hipStream_t stream) {
    const float* x  = (const float*)d_in[0];   // [N,2]
    const float* W1 = (const float*)d_in[1];   // [2,16]
    const float* b1 = (const float*)d_in[2];   // [16]
    const float* W2 = (const float*)d_in[3];   // [16,1]
    const float* b2 = (const float*)d_in[4];   // [1]
    const int*   ei = (const int*)d_in[5];     // [2,E]
    const int* src = ei;
    const int* dst = ei + E;

    // ws: hist[256K u32] | scanned[256K u32] | bsum[1024 u32] | degf[N] |
    //     dinv[N] | y[2N] | ax0[N] | ax1[N] | g2[N] | acc2[N] | scores[N]  (~6.6 MB)
    uint* hist_blocks = (uint*)d_ws;
    uint* scanned     = hist_blocks + NSCAN;
    uint* bsum        = scanned + NSCAN;
    float* degf       = (float*)(bsum + 1024);
    float* dinv       = degf + N;
    float2* y         = (float2*)(dinv + N);
    float* ax0        = (float*)(y + N);
    float* ax1        = ax0 + N;
    float* g2         = ax1 + N;
    float* acc2       = g2 + N;
    float* scores     = acc2 + N;

    // packed partitioned edges (16 MB) live in d_out — dead until k_out
    uint* part  = (uint*)d_out;
    float* out  = (float*)d_out;

    k_zero     <<<N / 256,     256, 0, stream>>>(degf);
    k_hist     <<<NBLK,        SCT, 0, stream>>>(dst, hist_blocks);
    k_scan_up  <<<NSCAN / 256, 256, 0, stream>>>(hist_blocks, bsum);
    k_scan_mid <<<1,           256, 0, stream>>>(bsum);
    k_scan_down<<<NSCAN / 256, 256, 0, stream>>>(hist_blocks, bsum, scanned);
    k_scatter  <<<NBLK,        SCT, 0, stream>>>(src, dst, scanned, part);
    k_deg      <<<NB * SPLIT,  256, 0, stream>>>(part, scanned, degf);
    k_dinv     <<<N / 256,     256, 0, stream>>>(x, degf, dinv, y, ax0, ax1);
    k_l1       <<<NB * SPLIT,  256, 0, stream>>>(part, scanned, y, ax0, ax1);
    k_node2    <<<N / 256,     256, 0, stream>>>(ax0, ax1, W1, b1, W2, dinv, g2, acc2);
    k_l2       <<<NB * SPLIT,  256, 0, stream>>>(part, scanned, g2, acc2);
    k_score    <<<N / 256,     256, 0, stream>>>(acc2, dinv, b2, scores);
    k_out      <<<E / 256,     256, 0, stream>>>(src, scores, out);
}

// Round 6
// 195.883 us; speedup vs baseline: 4.7232x; 1.1096x over previous
//
#include <hip/hip_runtime.h>
#include <cmath>

typedef unsigned int uint;

constexpr int N  = 131072;    // nodes
constexpr int E  = 4194304;   // edges (without self-loops)
constexpr int F  = 16;        // hidden width H1
constexpr int NB = 512;       // dst buckets of 256 nodes (bucket = dst>>8)
constexpr int NBLK  = 512;    // partition blocks
constexpr int SCT   = 512;    // threads per partition block
constexpr int CHUNK = 8192;   // edges per partition block (NBLK*CHUNK == E)
constexpr int EPT   = 16;     // edges per thread in partition kernels
constexpr int NSCAN = NB * NBLK;   // 262144 hist entries
constexpr int CAP   = 10240;  // LDS capacity per bucket in k_sort
                              // (bucket len ~ Binom(E,1/512): mean 8192, sd 90 -> 22 sd margin)

// ---- Phase A1: per-block bucket histogram (bucket-major storage) -----------
__global__ void k_hist(const int* __restrict__ dst, uint* __restrict__ hist_blocks) {
    __shared__ uint h[NB];
    int t = threadIdx.x, g = blockIdx.x;
    h[t] = 0;
    __syncthreads();
    int base = g * CHUNK;
#pragma unroll
    for (int k = 0; k < EPT; ++k)
        atomicAdd(&h[dst[base + k * SCT + t] >> 8], 1u);
    __syncthreads();
    hist_blocks[(size_t)t * NBLK + g] = h[t];   // [bucket][block]
}

// ---- hierarchical exclusive scan of hist_blocks (262144 elems) -------------
__global__ void k_scan_up(const uint* __restrict__ hist, uint* __restrict__ bsum) {
    __shared__ uint s[256];
    int g = blockIdx.x, t = threadIdx.x;
    s[t] = hist[(size_t)g * 256 + t];
    __syncthreads();
    for (int off = 128; off > 0; off >>= 1) {
        if (t < off) s[t] += s[t + off];
        __syncthreads();
    }
    if (t == 0) bsum[g] = s[0];
}

__global__ void k_scan_mid(uint* bsum) {   // 1024 elems, one block, exclusive in place
    __shared__ uint s[256];
    int t = threadIdx.x;
    uint v[4]; uint sum = 0;
#pragma unroll
    for (int k = 0; k < 4; ++k) { v[k] = bsum[t * 4 + k]; sum += v[k]; }
    s[t] = sum;
    __syncthreads();
    for (int off = 1; off < 256; off <<= 1) {
        uint x = (t >= off) ? s[t - off] : 0u;
        __syncthreads();
        s[t] += x;
        __syncthreads();
    }
    uint base = (t == 0) ? 0u : s[t - 1];
#pragma unroll
    for (int k = 0; k < 4; ++k) { uint old = v[k]; bsum[t * 4 + k] = base; base += old; }
}

__global__ void k_scan_down(const uint* __restrict__ hist, const uint* __restrict__ bsum,
                            uint* __restrict__ scanned) {
    __shared__ uint s[256];
    int g = blockIdx.x, t = threadIdx.x;
    uint v = hist[(size_t)g * 256 + t];
    s[t] = v;
    __syncthreads();
    for (int off = 1; off < 256; off <<= 1) {
        uint x = (t >= off) ? s[t - off] : 0u;
        __syncthreads();
        s[t] += x;
        __syncthreads();
    }
    scanned[(size_t)g * 256 + t] = bsum[g] + s[t] - v;   // exclusive
}

// ---- Phase A3: LDS-staged counting-sort scatter into buckets ---------------
__global__ void __launch_bounds__(SCT) k_scatter(
        const int* __restrict__ src, const int* __restrict__ dst,
        const uint* __restrict__ scanned, uint* __restrict__ part) {
    __shared__ uint h[NB];       // hist -> bump
    __shared__ uint sc[NB];      // scan temp (inclusive)
    __shared__ uint wb[NB];      // write_base[b] = scanned[b][g] - excl_local[b]
    __shared__ uint vals[CHUNK];
    __shared__ uint addr[CHUNK];
    int t = threadIdx.x, g = blockIdx.x;
    h[t] = 0;
    __syncthreads();
    int d[EPT], s[EPT];
    int base = g * CHUNK;
#pragma unroll
    for (int k = 0; k < EPT; ++k) {
        int e = base + k * SCT + t;
        d[k] = dst[e];
        s[k] = src[e];
        atomicAdd(&h[d[k] >> 8], 1u);
    }
    __syncthreads();
    uint v = h[t];
    sc[t] = v;
    __syncthreads();
    for (int off = 1; off < NB; off <<= 1) {      // Hillis-Steele inclusive, 512 wide
        uint x = (t >= off) ? sc[t - off] : 0u;
        __syncthreads();
        sc[t] += x;
        __syncthreads();
    }
    uint ex = sc[t] - v;                          // local exclusive prefix
    wb[t] = scanned[(size_t)t * NBLK + g] - ex;
    h[t] = ex;                                    // bump counter starts at excl
    __syncthreads();
#pragma unroll
    for (int k = 0; k < EPT; ++k) {
        int b = d[k] >> 8;
        uint slot = atomicAdd(&h[b], 1u);
        vals[slot] = ((uint)s[k] << 8) | (uint)(d[k] & 255);
        addr[slot] = wb[b] + slot;                // strictly ascending in slot
    }
    __syncthreads();
#pragma unroll
    for (int k = 0; k < EPT; ++k) {
        int i = k * SCT + t;
        part[addr[i]] = vals[i];
    }
}

// ---- Phase A4: per-bucket sort by dst-low -> CSR + dinv + y, in-place ------
// part[S0..S1) holds this bucket's packed edges (src<<8|dstlow).
// Output: part region overwritten with src sorted by dstlow; csr[node] offset;
// dinv[node]; y[node] = dinv*x[node].
__global__ void __launch_bounds__(SCT) k_sort(
        uint* part, const uint* __restrict__ scanned,
        const float* __restrict__ x,
        uint* __restrict__ csr, float* __restrict__ dinv, float2* __restrict__ y) {
    __shared__ uint cnt[256];
    __shared__ uint sc[256];
    __shared__ uint bump[256];
    __shared__ uint srt[CAP];
    int t = threadIdx.x, b = blockIdx.x;
    if (t < 256) cnt[t] = 0;
    __syncthreads();
    uint S0 = scanned[(size_t)b * NBLK];
    uint S1 = (b == NB - 1) ? (uint)E : scanned[(size_t)(b + 1) * NBLK];
    for (uint i = S0 + t; i < S1; i += SCT) atomicAdd(&cnt[part[i] & 255u], 1u);
    __syncthreads();
    if (t < 256) sc[t] = cnt[t];
    __syncthreads();
    for (int off = 1; off < 256; off <<= 1) {     // inclusive scan of 256 bins
        uint xx = 0;
        if (t < 256 && t >= off) xx = sc[t - off];
        __syncthreads();
        if (t < 256) sc[t] += xx;
        __syncthreads();
    }
    if (t < 256) bump[t] = sc[t] - cnt[t];        // exclusive
    __syncthreads();
    for (uint i = S0 + t; i < S1; i += SCT) {     // place (re-read part)
        uint pk = part[i];
        uint slot = atomicAdd(&bump[pk & 255u], 1u);
        srt[slot] = pk >> 8;                      // keep only src
    }
    __syncthreads();
    uint L = S1 - S0;
    for (uint i = t; i < L; i += SCT) part[S0 + i] = srt[i];   // coalesced flush
    if (t < 256) {
        int node = (b << 8) + t;
        uint ex = sc[t] - cnt[t];
        csr[node] = S0 + ex;
        float di = rsqrtf(1.0f + (float)cnt[t]);  // +1 self-loop
        dinv[node] = di;
        float2 xv = ((const float2*)x)[node];
        y[node] = make_float2(di * xv.x, di * xv.y);
    }
}

// ---- layer 1: CSR reduction (4 lanes/node) + fused MLP -> g2 ---------------
__global__ void k_l1(const uint* __restrict__ srcs, const uint* __restrict__ csr,
                     const float2* __restrict__ y, const float* __restrict__ dinv,
                     const float* __restrict__ W1, const float* __restrict__ b1,
                     const float* __restrict__ W2, float* __restrict__ g2) {
    int tid = blockIdx.x * blockDim.x + threadIdx.x;
    int node = tid >> 2, lane = tid & 3;
    uint o0 = csr[node];
    uint o1 = (node == N - 1) ? (uint)E : csr[node + 1];
    float A0 = 0.0f, A1 = 0.0f;
    for (uint j = o0 + lane; j < o1; j += 4) {
        float2 ys = y[srcs[j]];
        A0 += ys.x; A1 += ys.y;
    }
    A0 += __shfl_xor(A0, 1); A0 += __shfl_xor(A0, 2);   // all 4 lanes get sum
    A1 += __shfl_xor(A1, 1); A1 += __shfl_xor(A1, 2);
    float di = dinv[node];
    float2 yn = y[node];
    A0 = di * (A0 + yn.x);                              // + self-loop, * dinv[d]
    A1 = di * (A1 + yn.y);
    float acc = 0.0f;
#pragma unroll
    for (int f = lane; f < F; f += 4) {                 // 4 features per lane
        float v = fmaf(A0, W1[f], fmaf(A1, W1[F + f], b1[f]));
        acc = fmaf(fmaxf(v, 0.0f), W2[f], acc);
    }
    acc += __shfl_xor(acc, 1); acc += __shfl_xor(acc, 2);
    if (lane == 0) g2[node] = di * acc;
}

// ---- layer 2: CSR reduction (4 lanes/node) + sigmoid -> scores -------------
__global__ void k_l2(const uint* __restrict__ srcs, const uint* __restrict__ csr,
                     const float* __restrict__ g2, const float* __restrict__ dinv,
                     const float* __restrict__ b2, float* __restrict__ scores) {
    int tid = blockIdx.x * blockDim.x + threadIdx.x;
    int node = tid >> 2, lane = tid & 3;
    uint o0 = csr[node];
    uint o1 = (node == N - 1) ? (uint)E : csr[node + 1];
    float acc = 0.0f;
    for (uint j = o0 + lane; j < o1; j += 4) acc += g2[srcs[j]];
    acc += __shfl_xor(acc, 1); acc += __shfl_xor(acc, 2);
    if (lane == 0) {
        float v = fmaf(dinv[node], acc + g2[node], b2[0]);
        scores[node] = 1.0f / (1.0f + expf(-v));
    }
}

// ---- output gather: out[e] = scores[src[e]] --------------------------------
__global__ void k_out(const int* __restrict__ src, const float* __restrict__ scores,
                      float* __restrict__ out) {
    int e = blockIdx.x * blockDim.x + threadIdx.x;
    if (e < E) out[e] = scores[src[e]];
}

extern "C" void kernel_launch(void* const* d_in, const int* in_sizes, int n_in,
                              void* d_out, int out_size, void* d_ws, size_t ws_size,
                              hipStream_t stream) {
    const float* x  = (const float*)d_in[0];   // [N,2]
    const float* W1 = (const float*)d_in[1];   // [2,16]
    const float* b1 = (const float*)d_in[2];   // [16]
    const float* W2 = (const float*)d_in[3];   // [16,1]
    const float* b2 = (const float*)d_in[4];   // [1]
    const int*   ei = (const int*)d_in[5];     // [2,E]
    const int* src = ei;
    const int* dst = ei + E;

    // ws: hist[256K u32] | scanned[256K u32] | bsum[1024 u32] | csr[N+2 u32] |
    //     dinv[N f32] | y[N f32x2] | g2[N f32] | scores[N f32]   (~5.1 MB)
    uint* hist_blocks = (uint*)d_ws;
    uint* scanned     = hist_blocks + NSCAN;
    uint* bsum        = scanned + NSCAN;
    uint* csr         = bsum + 1024;
    float* dinv       = (float*)(csr + N + 2);
    float2* y         = (float2*)(dinv + N);
    float* g2         = (float*)(y + N);
    float* scores     = g2 + N;

    // bucket-sorted packed edges (16 MB) live in d_out; k_sort rewrites the
    // same region in place as dst-sorted src list; dead by the time k_out runs.
    uint* part  = (uint*)d_out;
    float* out  = (float*)d_out;

    k_hist     <<<NBLK,        SCT, 0, stream>>>(dst, hist_blocks);
    k_scan_up  <<<NSCAN / 256, 256, 0, stream>>>(hist_blocks, bsum);
    k_scan_mid <<<1,           256, 0, stream>>>(bsum);
    k_scan_down<<<NSCAN / 256, 256, 0, stream>>>(hist_blocks, bsum, scanned);
    k_scatter  <<<NBLK,        SCT, 0, stream>>>(src, dst, scanned, part);
    k_sort     <<<NB,          SCT, 0, stream>>>(part, scanned, x, csr, dinv, y);
    k_l1       <<<(N * 4) / 256, 256, 0, stream>>>(part, csr, y, dinv, W1, b1, W2, g2);
    k_l2       <<<(N * 4) / 256, 256, 0, stream>>>(part, csr, g2, dinv, b2, scores);
    k_out      <<<E / 256,     256, 0, stream>>>(src, scores, out);
}

// Round 7
// 191.280 us; speedup vs baseline: 4.8368x; 1.0241x over previous
//
#include <hip/hip_runtime.h>
#include <cmath>

typedef unsigned int uint;

constexpr int N  = 131072;    // nodes
constexpr int E  = 4194304;   // edges (without self-loops)
constexpr int F  = 16;        // hidden width H1
constexpr int NB = 512;       // dst buckets of 256 nodes (bucket = dst>>8)
constexpr int NBLK  = 512;    // partition blocks
constexpr int SCT   = 512;    // threads per partition block
constexpr int CHUNK = 8192;   // edges per partition block (NBLK*CHUNK == E)
constexpr int EPT   = 16;     // edges per thread in partition kernels
constexpr int NSCAN = NB * NBLK;   // 262144 hist entries
constexpr int CAP   = 10240;  // LDS capacity per bucket in k_sort (mean 8192, sd ~90)
constexpr int SLOTS = CAP / SCT;   // 20 register slots per thread in k_sort
constexpr int LPN   = 8;      // lanes per node in k_l1/k_l2

// ---- Phase A1: per-block bucket histogram, wave-private counters -----------
__global__ void __launch_bounds__(SCT) k_hist(const int* __restrict__ dst,
                                              uint* __restrict__ hist_blocks) {
    __shared__ uint hw[8 * NB];          // 8 wave-private hists (16 KB)
    int t = threadIdx.x, g = blockIdx.x;
    int w = t >> 6;
#pragma unroll
    for (int k = 0; k < 8; ++k) hw[k * SCT + t] = 0;
    __syncthreads();
    int base = g * CHUNK;
#pragma unroll
    for (int k = 0; k < EPT; ++k)
        atomicAdd(&hw[w * NB + (dst[base + k * SCT + t] >> 8)], 1u);
    __syncthreads();
    uint sum = 0;
#pragma unroll
    for (int k = 0; k < 8; ++k) sum += hw[k * NB + t];
    hist_blocks[(size_t)t * NBLK + g] = sum;   // [bucket][block]
}

// ---- hierarchical exclusive scan of hist_blocks (262144 elems) -------------
__global__ void k_scan_up(const uint* __restrict__ hist, uint* __restrict__ bsum) {
    __shared__ uint s[256];
    int g = blockIdx.x, t = threadIdx.x;
    s[t] = hist[(size_t)g * 256 + t];
    __syncthreads();
    for (int off = 128; off > 0; off >>= 1) {
        if (t < off) s[t] += s[t + off];
        __syncthreads();
    }
    if (t == 0) bsum[g] = s[0];
}

__global__ void k_scan_mid(uint* bsum) {   // 1024 elems, one block, exclusive in place
    __shared__ uint s[256];
    int t = threadIdx.x;
    uint v[4]; uint sum = 0;
#pragma unroll
    for (int k = 0; k < 4; ++k) { v[k] = bsum[t * 4 + k]; sum += v[k]; }
    s[t] = sum;
    __syncthreads();
    for (int off = 1; off < 256; off <<= 1) {
        uint x = (t >= off) ? s[t - off] : 0u;
        __syncthreads();
        s[t] += x;
        __syncthreads();
    }
    uint base = (t == 0) ? 0u : s[t - 1];
#pragma unroll
    for (int k = 0; k < 4; ++k) { uint old = v[k]; bsum[t * 4 + k] = base; base += old; }
}

__global__ void k_scan_down(const uint* __restrict__ hist, const uint* __restrict__ bsum,
                            uint* __restrict__ scanned) {
    __shared__ uint s[256];
    int g = blockIdx.x, t = threadIdx.x;
    uint v = hist[(size_t)g * 256 + t];
    s[t] = v;
    __syncthreads();
    for (int off = 1; off < 256; off <<= 1) {
        uint x = (t >= off) ? s[t - off] : 0u;
        __syncthreads();
        s[t] += x;
        __syncthreads();
    }
    scanned[(size_t)g * 256 + t] = bsum[g] + s[t] - v;   // exclusive
}

// ---- Phase A3: LDS-staged counting-sort scatter into buckets ---------------
__global__ void __launch_bounds__(SCT) k_scatter(
        const int* __restrict__ src, const int* __restrict__ dst,
        const uint* __restrict__ scanned, uint* __restrict__ part) {
    __shared__ uint h[NB];       // bin totals -> bump counters
    __shared__ uint wb[NB];      // write_base[b] = scanned[b][g] - excl_local[b]
    __shared__ uint wsum[8];
    __shared__ uint vals[CHUNK];
    __shared__ uint addr[CHUNK];
    int t = threadIdx.x, g = blockIdx.x;
    int lane = t & 63, w = t >> 6;
    h[t] = 0;
    __syncthreads();
    int d[EPT], s[EPT];
    int base = g * CHUNK;
#pragma unroll
    for (int k = 0; k < EPT; ++k) {
        int e = base + k * SCT + t;
        d[k] = dst[e];
        s[k] = src[e];
        atomicAdd(&h[d[k] >> 8], 1u);
    }
    __syncthreads();
    uint v = h[t];
    uint sv = v;                                  // wave-level inclusive scan
#pragma unroll
    for (int off = 1; off < 64; off <<= 1) {
        uint n = __shfl_up(sv, off);
        if (lane >= off) sv += n;
    }
    if (lane == 63) wsum[w] = sv;
    __syncthreads();
    uint wo = 0;
    for (int i = 0; i < w; ++i) wo += wsum[i];
    sv += wo;                                     // inclusive over 512 bins
    uint ex = sv - v;                             // local exclusive prefix
    wb[t] = scanned[(size_t)t * NBLK + g] - ex;
    h[t] = ex;                                    // bump starts at excl
    __syncthreads();
#pragma unroll
    for (int k = 0; k < EPT; ++k) {
        int b = d[k] >> 8;
        uint slot = atomicAdd(&h[b], 1u);
        vals[slot] = ((uint)s[k] << 8) | (uint)(d[k] & 255);
        addr[slot] = wb[b] + slot;                // ascending per bucket
    }
    __syncthreads();
#pragma unroll
    for (int k = 0; k < EPT; ++k) {
        int i = k * SCT + t;
        part[addr[i]] = vals[i];
    }
}

// ---- Phase A4: per-bucket sort by dst-low -> CSR + dinv + y, in place ------
// Single global read (register staging), wave-private counters.
__global__ void __launch_bounds__(SCT) k_sort(
        uint* part, const uint* __restrict__ scanned,
        const float* __restrict__ x,
        uint* __restrict__ csr, float* __restrict__ dinv, float2* __restrict__ y) {
    __shared__ uint hw[8 * 256];   // wave-private bin counters (8 KB)
    __shared__ uint cnt[256];      // per-bin totals
    __shared__ uint sc[256];       // inclusive scan of totals
    __shared__ uint wsum[4];
    __shared__ uint srt[CAP];
    int t = threadIdx.x, b = blockIdx.x;
    int lane = t & 63, w = t >> 6;
#pragma unroll
    for (int k = 0; k < 4; ++k) hw[k * SCT + t] = 0;
    __syncthreads();
    uint S0 = scanned[(size_t)b * NBLK];
    uint S1 = (b == NB - 1) ? (uint)E : scanned[(size_t)(b + 1) * NBLK];
    uint pk[SLOTS];
#pragma unroll
    for (int k = 0; k < SLOTS; ++k) {           // stage in registers, count
        uint i = S0 + (uint)(k * SCT + t);
        pk[k] = (i < S1) ? part[i] : 0xFFFFFFFFu;
        if (pk[k] != 0xFFFFFFFFu) atomicAdd(&hw[w * 256 + (pk[k] & 255u)], 1u);
    }
    __syncthreads();
    if (t < 256) {                               // wave-exclusive transform
        uint tot = 0;
#pragma unroll
        for (int k = 0; k < 8; ++k) {
            uint c = hw[k * 256 + t];
            hw[k * 256 + t] = tot;
            tot += c;
        }
        cnt[t] = tot;
        uint sv = tot;                           // shfl inclusive scan, 4 waves
#pragma unroll
        for (int off = 1; off < 64; off <<= 1) {
            uint n = __shfl_up(sv, off);
            if (lane >= off) sv += n;
        }
        if (lane == 63) wsum[t >> 6] = sv;
        sc[t] = sv;                              // partial (pre cross-wave)
    }
    __syncthreads();
    if (t < 256) {
        uint wo = 0;
        for (int i = 0; i < (t >> 6); ++i) wo += wsum[i];
        sc[t] += wo;                             // inclusive over 256 bins
    }
    __syncthreads();
#pragma unroll
    for (int k = 0; k < SLOTS; ++k) {            // place from registers
        if (pk[k] != 0xFFFFFFFFu) {
            uint bin = pk[k] & 255u;
            uint slot = (sc[bin] - cnt[bin]) + atomicAdd(&hw[w * 256 + bin], 1u);
            srt[slot] = pk[k] >> 8;              // keep only src
        }
    }
    __syncthreads();
    uint L = S1 - S0;
    for (uint i = t; i < L; i += SCT) part[S0 + i] = srt[i];   // coalesced flush
    if (t < 256) {
        int node = (b << 8) + t;
        csr[node] = S0 + (sc[t] - cnt[t]);
        float di = rsqrtf(1.0f + (float)cnt[t]);  // +1 self-loop
        dinv[node] = di;
        float2 xv = ((const float2*)x)[node];
        y[node] = make_float2(di * xv.x, di * xv.y);
    }
}

// ---- layer 1: CSR reduction (8 lanes/node) + fused MLP -> g2 ---------------
__global__ void k_l1(const uint* __restrict__ srcs, const uint* __restrict__ csr,
                     const float2* __restrict__ y, const float* __restrict__ dinv,
                     const float* __restrict__ W1, const float* __restrict__ b1,
                     const float* __restrict__ W2, float* __restrict__ g2) {
    int tid = blockIdx.x * blockDim.x + threadIdx.x;
    int node = tid >> 3, lane = tid & (LPN - 1);
    uint o0 = csr[node];
    uint o1 = (node == N - 1) ? (uint)E : csr[node + 1];
    float A0 = 0.0f, A1 = 0.0f;
    for (uint j = o0 + lane; j < o1; j += LPN) {
        float2 ys = y[srcs[j]];
        A0 += ys.x; A1 += ys.y;
    }
    A0 += __shfl_xor(A0, 1); A0 += __shfl_xor(A0, 2); A0 += __shfl_xor(A0, 4);
    A1 += __shfl_xor(A1, 1); A1 += __shfl_xor(A1, 2); A1 += __shfl_xor(A1, 4);
    float di = dinv[node];
    float2 yn = y[node];
    A0 = di * (A0 + yn.x);                              // + self-loop, * dinv[d]
    A1 = di * (A1 + yn.y);
    float acc = 0.0f;
#pragma unroll
    for (int f = lane; f < F; f += LPN) {               // 2 features per lane
        float v = fmaf(A0, W1[f], fmaf(A1, W1[F + f], b1[f]));
        acc = fmaf(fmaxf(v, 0.0f), W2[f], acc);
    }
    acc += __shfl_xor(acc, 1); acc += __shfl_xor(acc, 2); acc += __shfl_xor(acc, 4);
    if (lane == 0) g2[node] = di * acc;
}

// ---- layer 2: CSR reduction (8 lanes/node) + sigmoid -> scores -------------
__global__ void k_l2(const uint* __restrict__ srcs, const uint* __restrict__ csr,
                     const float* __restrict__ g2, const float* __restrict__ dinv,
                     const float* __restrict__ b2, float* __restrict__ scores) {
    int tid = blockIdx.x * blockDim.x + threadIdx.x;
    int node = tid >> 3, lane = tid & (LPN - 1);
    uint o0 = csr[node];
    uint o1 = (node == N - 1) ? (uint)E : csr[node + 1];
    float acc = 0.0f;
    for (uint j = o0 + lane; j < o1; j += LPN) acc += g2[srcs[j]];
    acc += __shfl_xor(acc, 1); acc += __shfl_xor(acc, 2); acc += __shfl_xor(acc, 4);
    if (lane == 0) {
        float v = fmaf(dinv[node], acc + g2[node], b2[0]);
        scores[node] = 1.0f / (1.0f + expf(-v));
    }
}

// ---- output gather: out[e] = scores[src[e]] --------------------------------
__global__ void k_out(const int* __restrict__ src, const float* __restrict__ scores,
                      float* __restrict__ out) {
    int e = blockIdx.x * blockDim.x + threadIdx.x;
    if (e < E) out[e] = scores[src[e]];
}

extern "C" void kernel_launch(void* const* d_in, const int* in_sizes, int n_in,
                              void* d_out, int out_size, void* d_ws, size_t ws_size,
                              hipStream_t stream) {
    const float* x  = (const float*)d_in[0];   // [N,2]
    const float* W1 = (const float*)d_in[1];   // [2,16]
    const float* b1 = (const float*)d_in[2];   // [16]
    const float* W2 = (const float*)d_in[3];   // [16,1]
    const float* b2 = (const float*)d_in[4];   // [1]
    const int*   ei = (const int*)d_in[5];     // [2,E]
    const int* src = ei;
    const int* dst = ei + E;

    // ws: hist[256K u32] | scanned[256K u32] | bsum[1024 u32] | csr[N+2 u32] |
    //     dinv[N f32] | y[N f32x2] | g2[N f32] | scores[N f32]   (~5.1 MB)
    uint* hist_blocks = (uint*)d_ws;
    uint* scanned     = hist_blocks + NSCAN;
    uint* bsum        = scanned + NSCAN;
    uint* csr         = bsum + 1024;
    float* dinv       = (float*)(csr + N + 2);
    float2* y         = (float2*)(dinv + N);
    float* g2         = (float*)(y + N);
    float* scores     = g2 + N;

    // bucket-sorted packed edges (16 MB) live in d_out; k_sort rewrites the
    // same region in place as dst-sorted src list; dead by the time k_out runs.
    uint* part  = (uint*)d_out;
    float* out  = (float*)d_out;

    k_hist     <<<NBLK,          SCT, 0, stream>>>(dst, hist_blocks);
    k_scan_up  <<<NSCAN / 256,   256, 0, stream>>>(hist_blocks, bsum);
    k_scan_mid <<<1,             256, 0, stream>>>(bsum);
    k_scan_down<<<NSCAN / 256,   256, 0, stream>>>(hist_blocks, bsum, scanned);
    k_scatter  <<<NBLK,          SCT, 0, stream>>>(src, dst, scanned, part);
    k_sort     <<<NB,            SCT, 0, stream>>>(part, scanned, x, csr, dinv, y);
    k_l1       <<<(N * LPN) / 256, 256, 0, stream>>>(part, csr, y, dinv, W1, b1, W2, g2);
    k_l2       <<<(N * LPN) / 256, 256, 0, stream>>>(part, csr, g2, dinv, b2, scores);
    k_out      <<<E / 256,       256, 0, stream>>>(src, scores, out);
}

// Round 8
// 190.367 us; speedup vs baseline: 4.8600x; 1.0048x over previous
//
#include <hip/hip_runtime.h>
#include <cmath>

typedef unsigned int uint;

constexpr int N  = 131072;    // nodes
constexpr int E  = 4194304;   // edges (without self-loops)
constexpr int F  = 16;        // hidden width H1
constexpr int NB = 512;       // dst buckets of 256 nodes (bucket = dst>>8)
constexpr int NBLK  = 512;    // partition blocks
constexpr int SCT   = 512;    // threads per partition block
constexpr int CHUNK = 8192;   // edges per partition block (NBLK*CHUNK == E)
constexpr int EPT   = 16;     // edges per thread in partition kernels
constexpr int NSCAN = NB * NBLK;   // 262144 hist entries
constexpr int CAP   = 10240;  // LDS capacity per bucket in k_sort (mean 8192, sd ~90)
constexpr int SLOTS = CAP / SCT;   // 20 register slots per thread in k_sort
constexpr int LPN   = 16;     // lanes per node in k_l1/k_l2 (== F)

// ---- Phase A1: per-block bucket histogram, wave-private counters, int4 loads
__global__ void __launch_bounds__(SCT) k_hist(const int* __restrict__ dst,
                                              uint* __restrict__ hist_blocks) {
    __shared__ uint hw[8 * NB];          // 8 wave-private hists (16 KB)
    int t = threadIdx.x, g = blockIdx.x;
    int w = t >> 6;
#pragma unroll
    for (int k = 0; k < 8; ++k) hw[k * SCT + t] = 0;
    __syncthreads();
    const int4* dst4 = (const int4*)dst;
    int base4 = g * (CHUNK / 4);
#pragma unroll
    for (int k = 0; k < EPT / 4; ++k) {
        int4 d4 = dst4[base4 + k * SCT + t];
        atomicAdd(&hw[w * NB + (d4.x >> 8)], 1u);
        atomicAdd(&hw[w * NB + (d4.y >> 8)], 1u);
        atomicAdd(&hw[w * NB + (d4.z >> 8)], 1u);
        atomicAdd(&hw[w * NB + (d4.w >> 8)], 1u);
    }
    __syncthreads();
    uint sum = 0;
#pragma unroll
    for (int k = 0; k < 8; ++k) sum += hw[k * NB + t];
    hist_blocks[(size_t)t * NBLK + g] = sum;   // [bucket][block]
}

// ---- scan step 1: tile sums (1024 tiles of 256) ----------------------------
__global__ void k_scan_up(const uint* __restrict__ hist, uint* __restrict__ bsum) {
    __shared__ uint s[256];
    int g = blockIdx.x, t = threadIdx.x;
    s[t] = hist[(size_t)g * 256 + t];
    __syncthreads();
    for (int off = 128; off > 0; off >>= 1) {
        if (t < off) s[t] += s[t + off];
        __syncthreads();
    }
    if (t == 0) bsum[g] = s[0];
}

// ---- scan step 2: per-tile base (masked reduction over bsum) + local scan --
__global__ void k_scan_down(const uint* __restrict__ hist, const uint* __restrict__ bsum,
                            uint* __restrict__ scanned) {
    __shared__ uint red[256];
    __shared__ uint s[256];
    int g = blockIdx.x, t = threadIdx.x;
    uint p = 0;
    for (int i = t; i < g; i += 256) p += bsum[i];   // sum of tiles before g
    red[t] = p;
    __syncthreads();
    for (int off = 128; off > 0; off >>= 1) {
        if (t < off) red[t] += red[t + off];
        __syncthreads();
    }
    uint base = red[0];
    uint v = hist[(size_t)g * 256 + t];
    s[t] = v;
    __syncthreads();
    for (int off = 1; off < 256; off <<= 1) {
        uint x = (t >= off) ? s[t - off] : 0u;
        __syncthreads();
        s[t] += x;
        __syncthreads();
    }
    scanned[(size_t)g * 256 + t] = base + s[t] - v;   // exclusive
}

// ---- Phase A3: LDS-staged counting-sort scatter into buckets, int4 loads ---
__global__ void __launch_bounds__(SCT) k_scatter(
        const int* __restrict__ src, const int* __restrict__ dst,
        const uint* __restrict__ scanned, uint* __restrict__ part) {
    __shared__ uint h[NB];       // bin totals -> bump counters
    __shared__ uint wb[NB];      // write_base[b] = scanned[b][g] - excl_local[b]
    __shared__ uint wsum[8];
    __shared__ uint vals[CHUNK];
    __shared__ uint addr[CHUNK];
    int t = threadIdx.x, g = blockIdx.x;
    int lane = t & 63, w = t >> 6;
    h[t] = 0;
    __syncthreads();
    int d[EPT], s[EPT];
    const int4* src4 = (const int4*)src;
    const int4* dst4 = (const int4*)dst;
    int base4 = g * (CHUNK / 4);
#pragma unroll
    for (int k = 0; k < EPT / 4; ++k) {
        int4 d4 = dst4[base4 + k * SCT + t];
        int4 s4 = src4[base4 + k * SCT + t];
        d[4 * k + 0] = d4.x; d[4 * k + 1] = d4.y; d[4 * k + 2] = d4.z; d[4 * k + 3] = d4.w;
        s[4 * k + 0] = s4.x; s[4 * k + 1] = s4.y; s[4 * k + 2] = s4.z; s[4 * k + 3] = s4.w;
        atomicAdd(&h[d4.x >> 8], 1u);
        atomicAdd(&h[d4.y >> 8], 1u);
        atomicAdd(&h[d4.z >> 8], 1u);
        atomicAdd(&h[d4.w >> 8], 1u);
    }
    __syncthreads();
    uint v = h[t];
    uint sv = v;                                  // wave-level inclusive scan
#pragma unroll
    for (int off = 1; off < 64; off <<= 1) {
        uint n = __shfl_up(sv, off);
        if (lane >= off) sv += n;
    }
    if (lane == 63) wsum[w] = sv;
    __syncthreads();
    uint wo = 0;
    for (int i = 0; i < w; ++i) wo += wsum[i];
    sv += wo;                                     // inclusive over 512 bins
    uint ex = sv - v;                             // local exclusive prefix
    wb[t] = scanned[(size_t)t * NBLK + g] - ex;
    h[t] = ex;                                    // bump starts at excl
    __syncthreads();
#pragma unroll
    for (int k = 0; k < EPT; ++k) {
        int b = d[k] >> 8;
        uint slot = atomicAdd(&h[b], 1u);
        vals[slot] = ((uint)s[k] << 8) | (uint)(d[k] & 255);
        addr[slot] = wb[b] + slot;                // ascending per bucket
    }
    __syncthreads();
#pragma unroll
    for (int k = 0; k < EPT; ++k) {
        int i = k * SCT + t;
        part[addr[i]] = vals[i];
    }
}

// ---- Phase A4: per-bucket sort by dst-low -> CSR + dinv + y, in place ------
__global__ void __launch_bounds__(SCT) k_sort(
        uint* part, const uint* __restrict__ scanned,
        const float* __restrict__ x,
        uint* __restrict__ csr, float* __restrict__ dinv, float2* __restrict__ y) {
    __shared__ uint hw[8 * 256];   // wave-private bin counters (8 KB)
    __shared__ uint cnt[256];      // per-bin totals
    __shared__ uint sc[256];       // inclusive scan of totals
    __shared__ uint wsum[4];
    __shared__ uint srt[CAP];
    int t = threadIdx.x, b = blockIdx.x;
    int lane = t & 63, w = t >> 6;
#pragma unroll
    for (int k = 0; k < 4; ++k) hw[k * SCT + t] = 0;
    __syncthreads();
    uint S0 = scanned[(size_t)b * NBLK];
    uint S1 = (b == NB - 1) ? (uint)E : scanned[(size_t)(b + 1) * NBLK];
    uint pk[SLOTS];
#pragma unroll
    for (int k = 0; k < SLOTS; ++k) {           // stage in registers, count
        uint i = S0 + (uint)(k * SCT + t);
        pk[k] = (i < S1) ? part[i] : 0xFFFFFFFFu;
        if (pk[k] != 0xFFFFFFFFu) atomicAdd(&hw[w * 256 + (pk[k] & 255u)], 1u);
    }
    __syncthreads();
    if (t < 256) {                               // wave-exclusive transform
        uint tot = 0;
#pragma unroll
        for (int k = 0; k < 8; ++k) {
            uint c = hw[k * 256 + t];
            hw[k * 256 + t] = tot;
            tot += c;
        }
        cnt[t] = tot;
        uint sv = tot;                           // shfl inclusive scan, 4 waves
#pragma unroll
        for (int off = 1; off < 64; off <<= 1) {
            uint n = __shfl_up(sv, off);
            if (lane >= off) sv += n;
        }
        if (lane == 63) wsum[t >> 6] = sv;
        sc[t] = sv;                              // partial (pre cross-wave)
    }
    __syncthreads();
    if (t < 256) {
        uint wo = 0;
        for (int i = 0; i < (t >> 6); ++i) wo += wsum[i];
        sc[t] += wo;                             // inclusive over 256 bins
    }
    __syncthreads();
#pragma unroll
    for (int k = 0; k < SLOTS; ++k) {            // place from registers
        if (pk[k] != 0xFFFFFFFFu) {
            uint bin = pk[k] & 255u;
            uint slot = (sc[bin] - cnt[bin]) + atomicAdd(&hw[w * 256 + bin], 1u);
            srt[slot] = pk[k] >> 8;              // keep only src
        }
    }
    __syncthreads();
    uint L = S1 - S0;
    for (uint i = t; i < L; i += SCT) part[S0 + i] = srt[i];   // coalesced flush
    if (t < 256) {
        int node = (b << 8) + t;
        csr[node] = S0 + (sc[t] - cnt[t]);
        float di = rsqrtf(1.0f + (float)cnt[t]);  // +1 self-loop
        dinv[node] = di;
        float2 xv = ((const float2*)x)[node];
        y[node] = make_float2(di * xv.x, di * xv.y);
    }
}

// ---- layer 1: CSR reduction (16 lanes/node) + one-feature-per-lane MLP -----
__global__ void k_l1(const uint* __restrict__ srcs, const uint* __restrict__ csr,
                     const float2* __restrict__ y, const float* __restrict__ dinv,
                     const float* __restrict__ W1, const float* __restrict__ b1,
                     const float* __restrict__ W2, float* __restrict__ g2) {
    int tid = blockIdx.x * blockDim.x + threadIdx.x;
    int node = tid >> 4, lane = tid & (LPN - 1);
    uint o0 = csr[node];
    uint o1 = (node == N - 1) ? (uint)E : csr[node + 1];
    float A0 = 0.0f, A1 = 0.0f;
    for (uint j = o0 + lane; j < o1; j += LPN) {
        float2 ys = y[srcs[j]];
        A0 += ys.x; A1 += ys.y;
    }
    A0 += __shfl_xor(A0, 1); A0 += __shfl_xor(A0, 2);
    A0 += __shfl_xor(A0, 4); A0 += __shfl_xor(A0, 8);
    A1 += __shfl_xor(A1, 1); A1 += __shfl_xor(A1, 2);
    A1 += __shfl_xor(A1, 4); A1 += __shfl_xor(A1, 8);
    float di = dinv[node];
    float2 yn = y[node];
    A0 = di * (A0 + yn.x);                              // + self-loop, * dinv[d]
    A1 = di * (A1 + yn.y);
    int f = lane;                                       // exactly one feature/lane
    float v = fmaf(A0, W1[f], fmaf(A1, W1[F + f], b1[f]));
    float acc = fmaxf(v, 0.0f) * W2[f];
    acc += __shfl_xor(acc, 1); acc += __shfl_xor(acc, 2);
    acc += __shfl_xor(acc, 4); acc += __shfl_xor(acc, 8);
    if (lane == 0) g2[node] = di * acc;
}

// ---- layer 2: CSR reduction (16 lanes/node) + sigmoid -> scores ------------
__global__ void k_l2(const uint* __restrict__ srcs, const uint* __restrict__ csr,
                     const float* __restrict__ g2, const float* __restrict__ dinv,
                     const float* __restrict__ b2, float* __restrict__ scores) {
    int tid = blockIdx.x * blockDim.x + threadIdx.x;
    int node = tid >> 4, lane = tid & (LPN - 1);
    uint o0 = csr[node];
    uint o1 = (node == N - 1) ? (uint)E : csr[node + 1];
    float acc = 0.0f;
    for (uint j = o0 + lane; j < o1; j += LPN) acc += g2[srcs[j]];
    acc += __shfl_xor(acc, 1); acc += __shfl_xor(acc, 2);
    acc += __shfl_xor(acc, 4); acc += __shfl_xor(acc, 8);
    if (lane == 0) {
        float v = fmaf(dinv[node], acc + g2[node], b2[0]);
        scores[node] = 1.0f / (1.0f + expf(-v));
    }
}

// ---- output gather: out[e] = scores[src[e]], 4 edges/thread ----------------
__global__ void k_out(const int* __restrict__ src, const float* __restrict__ scores,
                      float* __restrict__ out) {
    int i = blockIdx.x * blockDim.x + threadIdx.x;
    if (i >= E / 4) return;
    int4 s4 = ((const int4*)src)[i];
    float4 o;
    o.x = scores[s4.x];
    o.y = scores[s4.y];
    o.z = scores[s4.z];
    o.w = scores[s4.w];
    ((float4*)out)[i] = o;
}

extern "C" void kernel_launch(void* const* d_in, const int* in_sizes, int n_in,
                              void* d_out, int out_size, void* d_ws, size_t ws_size,
                              hipStream_t stream) {
    const float* x  = (const float*)d_in[0];   // [N,2]
    const float* W1 = (const float*)d_in[1];   // [2,16]
    const float* b1 = (const float*)d_in[2];   // [16]
    const float* W2 = (const float*)d_in[3];   // [16,1]
    const float* b2 = (const float*)d_in[4];   // [1]
    const int*   ei = (const int*)d_in[5];     // [2,E]
    const int* src = ei;
    const int* dst = ei + E;

    // ws: hist[256K u32] | scanned[256K u32] | bsum[1024 u32] | csr[N+2 u32] |
    //     dinv[N f32] | y[N f32x2] | g2[N f32] | scores[N f32]   (~5.1 MB)
    uint* hist_blocks = (uint*)d_ws;
    uint* scanned     = hist_blocks + NSCAN;
    uint* bsum        = scanned + NSCAN;
    uint* csr         = bsum + 1024;
    float* dinv       = (float*)(csr + N + 2);
    float2* y         = (float2*)(dinv + N);
    float* g2         = (float*)(y + N);
    float* scores     = g2 + N;

    // bucket-sorted packed edges (16 MB) live in d_out; k_sort rewrites the
    // same region in place as dst-sorted src list; dead by the time k_out runs.
    uint* part  = (uint*)d_out;
    float* out  = (float*)d_out;

    k_hist     <<<NBLK,          SCT, 0, stream>>>(dst, hist_blocks);
    k_scan_up  <<<NSCAN / 256,   256, 0, stream>>>(hist_blocks, bsum);
    k_scan_down<<<NSCAN / 256,   256, 0, stream>>>(hist_blocks, bsum, scanned);
    k_scatter  <<<NBLK,          SCT, 0, stream>>>(src, dst, scanned, part);
    k_sort     <<<NB,            SCT, 0, stream>>>(part, scanned, x, csr, dinv, y);
    k_l1       <<<(N * LPN) / 256, 256, 0, stream>>>(part, csr, y, dinv, W1, b1, W2, g2);
    k_l2       <<<(N * LPN) / 256, 256, 0, stream>>>(part, csr, g2, dinv, b2, scores);
    k_out      <<<E / 4 / 256,   256, 0, stream>>>(src, scores, out);
}